// Round 16
// baseline (246.606 us; speedup 1.0000x reference)
//
#include <hip/hip_runtime.h>
#include <math.h>

#define NS 1024
#define DM 512
#define NH 8
#define DEPTH 64

// ws offsets (floats). Lifetimes:
//  QH/KH: f16 hi+lo qh/kh (k_proj -> k_score) -> reused as CTX0/CTX1 (k_pv/k_out).
//  VH: fp32 vh (k_proj -> k_pv), then wo bricks (k_prep_wo -> k_out).
// aux f16 plane (8MB) lives in d_out's out region (dead until k_out).
#define OFF_QH   0
#define OFF_KH   2097152
#define OFF_VH   4194304
#define OFF_CTX0 0
#define OFF_CTX1 2097152
#define OFF_PART 6291456

#define ESW(row, col) ((col) ^ ((((row) >> 3) & 7) << 2))   // rows 0..63 scatter

#define LO_SCALE 2048.0f
#define LO_INV   (1.0f/2048.0f)
#define F16_MIN_NORM 6.1035156e-5f
#define ASCALE   4096.0f
#define AUNSCALE (1.0f/4096.0f)

typedef float f4 __attribute__((ext_vector_type(4)));
typedef _Float16 h8 __attribute__((ext_vector_type(8)));
typedef _Float16 h4 __attribute__((ext_vector_type(4)));
typedef float f32x4v __attribute__((ext_vector_type(4)));

// guarded hi + scaled lo (for small-magnitude data: weights, ctx)
#define SPLIT1(x, hi_e, lo_e) {                                          \
    const float x_ = (x);                                                \
    _Float16 t = (fabsf(x_) >= F16_MIN_NORM) ? (_Float16)x_ : (_Float16)0.f; \
    hi_e = t;                                                            \
    lo_e = (_Float16)((x_ - (float)t) * LO_SCALE);                       \
}

#define SPLIT8(u0, u1, hi, lo) {                                         \
    SPLIT1(u0.x, hi[0], lo[0]) SPLIT1(u0.y, hi[1], lo[1])                \
    SPLIT1(u0.z, hi[2], lo[2]) SPLIT1(u0.w, hi[3], lo[3])                \
    SPLIT1(u1.x, hi[4], lo[4]) SPLIT1(u1.y, hi[5], lo[5])                \
    SPLIT1(u1.z, hi[6], lo[6]) SPLIT1(u1.w, hi[7], lo[7])                \
}

// 3-MFMA scaled split product (separate accM, for LO_SCALE'd operands)
#define MM(accH, accM, a_h, a_l, b_h, b_l) {                                   \
    accH = __builtin_amdgcn_mfma_f32_16x16x32_f16(a_h, b_h, accH, 0, 0, 0);    \
    accM = __builtin_amdgcn_mfma_f32_16x16x32_f16(a_l, b_h, accM, 0, 0, 0);    \
    accM = __builtin_amdgcn_mfma_f32_16x16x32_f16(a_h, b_l, accM, 0, 0, 0);    \
}
// 3-MFMA unscaled split product (O(1) data: lo is fp16-normal, one acc)
#define MM1(acc, a_h, a_l, b_h, b_l) {                                         \
    acc = __builtin_amdgcn_mfma_f32_16x16x32_f16(a_h, b_h, acc, 0, 0, 0);      \
    acc = __builtin_amdgcn_mfma_f32_16x16x32_f16(a_l, b_h, acc, 0, 0, 0);      \
    acc = __builtin_amdgcn_mfma_f32_16x16x32_f16(a_h, b_l, acc, 0, 0, 0);      \
}

// ---- prep body: W fp32 -> fp16 hi + scaled-lo bricks (262144 halves each)
__device__ __forceinline__ void prep_one(
    const float* __restrict__ W, _Float16* __restrict__ whi,
    _Float16* __restrict__ wlo, int g)
{
    const int kk = g >> 7;
    const int n  = (g & 127) * 4;
    const float4 f = *(const float4*)(W + (size_t)kk * DM + n);
    const int gbase = (kk >> 3) * 128 + (kk & 7);
    #define PREP1(val, nn) {                                             \
        const int a_ = ((nn) >> 4) * 8192 + gbase + ((nn) & 15) * 8;     \
        _Float16 h_; _Float16 l_;                                        \
        SPLIT1(val, h_, l_)                                              \
        whi[a_] = h_; wlo[a_] = l_;                                      \
    }
    PREP1(f.x, n + 0) PREP1(f.y, n + 1) PREP1(f.z, n + 2) PREP1(f.w, n + 3)
    #undef PREP1
}

__global__ __launch_bounds__(256) void k_prep_qkv(
    const float* __restrict__ wq, const float* __restrict__ wk,
    const float* __restrict__ wv, float* __restrict__ attn)
{
    const int w = blockIdx.y;
    const float* W = (w == 0) ? wq : (w == 1) ? wk : wv;
    _Float16* base = (_Float16*)attn + (size_t)w * 524288;
    prep_one(W, base, base + 262144, blockIdx.x * 256 + threadIdx.x);
}

__global__ __launch_bounds__(256) void k_prep_wo(
    const float* __restrict__ wo, float* __restrict__ ws)
{
    _Float16* base = (_Float16*)(ws + OFF_VH);
    prep_one(wo, base, base + 262144, blockIdx.x * 256 + threadIdx.x);
}

// ---- aux fold: aux[b][i][j] = f16( mask*(-1e9*at) + hb*t_hb + pi*t_pi ), clamped.
__global__ __launch_bounds__(256) void k_prep_aux(
    const float* __restrict__ mask, const float* __restrict__ t_hb,
    const float* __restrict__ t_pi,
    const float* __restrict__ aug_hb, const float* __restrict__ aug_pi,
    const float* __restrict__ aug_at, const int* __restrict__ bnum,
    float* __restrict__ outp)
{
    const int g = blockIdx.x * 256 + threadIdx.x;       // 0..1M-1
    const size_t e0 = (size_t)g * 4;
    const size_t t0 = e0 & (size_t)(NS*NS - 1);
    const int bn = bnum[0];
    const float at = aug_at[bn], hb = aug_hb[bn], pi = aug_pi[bn];
    const float m_at = -1e9f * at;
    const f4 m4 = *(const f4*)(mask + e0);
    const f4 th = *(const f4*)(t_hb + t0);
    const f4 tp = *(const f4*)(t_pi + t0);
    h4 o;
    float a;
    a = fmaf(m4.x, m_at, fmaf(hb, th.x, pi*tp.x)); if (a < -60000.f) a = -60000.f; o[0] = (_Float16)a;
    a = fmaf(m4.y, m_at, fmaf(hb, th.y, pi*tp.y)); if (a < -60000.f) a = -60000.f; o[1] = (_Float16)a;
    a = fmaf(m4.z, m_at, fmaf(hb, th.z, pi*tp.z)); if (a < -60000.f) a = -60000.f; o[2] = (_Float16)a;
    a = fmaf(m4.w, m_at, fmaf(hb, th.w, pi*tp.w)); if (a < -60000.f) a = -60000.f; o[3] = (_Float16)a;
    *(h4*)((_Float16*)outp + e0) = o;
}

// ---------------- QKV projection via fp16-split MFMA: X@W+b -> split heads
__global__ __launch_bounds__(256, 3) void k_proj(
    const float* __restrict__ q, const float* __restrict__ k, const float* __restrict__ v,
    const float* __restrict__ bq, const float* __restrict__ bk, const float* __restrict__ bv,
    float* __restrict__ ws, const float* __restrict__ attn)
{
    const float *X, *bias; int wsel;
    if (blockIdx.z == 0)      { X=q; bias=bq; wsel=0; }
    else if (blockIdx.z == 1) { X=k; bias=bk; wsel=1; }
    else                      { X=v; bias=bv; wsel=2; }
    float* outf = ws + OFF_VH;                       // v only
    _Float16* outh = (_Float16*)(ws + (wsel == 0 ? OFF_QH : OFF_KH));  // q/k

    const int f = blockIdx.x + (blockIdx.y << 3);       // 0..255
    const int n0 = (f >> 5) * 64, m0 = (f & 31) * 128;
    const int tid = threadIdx.x, l = tid & 63, w = tid >> 6;
    const int lr = l & 15, lg = l >> 4;

    const _Float16* whi = (const _Float16*)attn + (size_t)wsel * 524288;
    const _Float16* wlo = whi + 262144;
    const float* ap0 = X + (size_t)(m0 + w*32 + lr) * DM + lg*8;
    const float* ap1 = ap0 + (size_t)16 * DM;
    const _Float16* bh_base = whi + (size_t)(n0 >> 4) * 8192 + lg*128 + lr*8;
    const _Float16* bl_base = wlo + (size_t)(n0 >> 4) * 8192 + lg*128 + lr*8;

    f32x4v aH00 = 0, aH01 = 0, aH02 = 0, aH03 = 0;
    f32x4v aH10 = 0, aH11 = 0, aH12 = 0, aH13 = 0;
    f32x4v aM00 = 0, aM01 = 0, aM02 = 0, aM03 = 0;
    f32x4v aM10 = 0, aM11 = 0, aM12 = 0, aM13 = 0;

    #pragma unroll 1
    for (int kb = 0; kb < DM; kb += 32) {
        h8 ah0, al0, ah1, al1;
        {
            const float4 u0 = *(const float4*)(ap0 + kb);
            const float4 u1 = *(const float4*)(ap0 + kb + 4);
            SPLIT8(u0, u1, ah0, al0);
            const float4 v0 = *(const float4*)(ap1 + kb);
            const float4 v1 = *(const float4*)(ap1 + kb + 4);
            SPLIT8(v0, v1, ah1, al1);
        }
        const int boff = kb * 16;
        const h8 bh0 = *(const h8*)(bh_base + boff);
        const h8 bh1 = *(const h8*)(bh_base + boff + 8192);
        const h8 bh2 = *(const h8*)(bh_base + boff + 16384);
        const h8 bh3 = *(const h8*)(bh_base + boff + 24576);
        const h8 bl0 = *(const h8*)(bl_base + boff);
        const h8 bl1 = *(const h8*)(bl_base + boff + 8192);
        const h8 bl2 = *(const h8*)(bl_base + boff + 16384);
        const h8 bl3 = *(const h8*)(bl_base + boff + 24576);

        MM(aH00, aM00, ah0, al0, bh0, bl0) MM(aH01, aM01, ah0, al0, bh1, bl1)
        MM(aH02, aM02, ah0, al0, bh2, bl2) MM(aH03, aM03, ah0, al0, bh3, bl3)
        MM(aH10, aM10, ah1, al1, bh0, bl0) MM(aH11, aM11, ah1, al1, bh1, bl1)
        MM(aH12, aM12, ah1, al1, bh2, bl2) MM(aH13, aM13, ah1, al1, bh3, bl3)
    }

    const int h = n0 >> 6;
    #define STORE_TILE(accH, accM, nt, mt) {                                 \
        const int n = n0 + (nt)*16 + lr;                                     \
        const float bsv = bias[n];                                           \
        const int d = n & 63;                                                \
        const int mbase = m0 + w*32 + (mt)*16 + lg*4;                        \
        _Pragma("unroll")                                                    \
        for (int r = 0; r < 4; ++r) {                                        \
            const int m = mbase + r;                                         \
            const int bb = m >> 10, s = m & 1023;                            \
            const float val = fmaf(accM[r], LO_INV, accH[r]) + bsv;          \
            if (wsel == 2) {                                                 \
                outf[(((size_t)(bb*NH + h))*NS + s)*DEPTH + d] = val;        \
            } else {                                                         \
                _Float16* p = outh + (size_t)(bb*NH + h)*131072              \
                                   + (size_t)s*64 + d;                       \
                const _Float16 hi_ = (_Float16)val;                          \
                p[0]     = hi_;                                              \
                p[65536] = (_Float16)(val - (float)hi_);                     \
            }                                                                \
        }                                                                    \
    }
    STORE_TILE(aH00, aM00, 0, 0) STORE_TILE(aH10, aM10, 0, 1)
    STORE_TILE(aH01, aM01, 1, 0) STORE_TILE(aH11, aM11, 1, 1)
    STORE_TILE(aH02, aM02, 2, 0) STORE_TILE(aH12, aM12, 2, 1)
    STORE_TILE(aH03, aM03, 3, 0) STORE_TILE(aH13, aM13, 3, 1)
    #undef STORE_TILE
}

// ---------------- k_score: S = K.Q^T via MFMA, e = exp(acc*sc_at + aux) -> nt-f4 write + sums
// 128x128 block tile, 8 waves (512 thr) x (32j x 64i): acc[2][4]=32 regs/thread,
// launch_bounds(512,6) -> VGPR<=85, 6 waves/SIMD = 75% occupancy (R13 was 38% @ 3 blocks).
__global__ __launch_bounds__(512, 6) void k_score(
    float* __restrict__ ws,
    const _Float16* __restrict__ aux,
    const float* __restrict__ aug_at, const int* __restrict__ bnum,
    float* __restrict__ attn)
{
    __shared__ float wred[8];
    const int bh = blockIdx.z, b = bh >> 3;
    const int f = blockIdx.x + (blockIdx.y << 3);  // 0..63, rect XCD grouping
    const int r = f & 7, qq = f >> 3;
    const int it = ((r & 1) << 2) | (qq & 3);
    const int jt_ = ((r >> 1) << 1) | (qq >> 2);
    const int i0 = it * 128, j0 = jt_ * 128;
    const _Float16* kb_ = (const _Float16*)(ws + OFF_KH) + (size_t)bh * 131072;
    const _Float16* qb_ = (const _Float16*)(ws + OFF_QH) + (size_t)bh * 131072;
    const int tid = threadIdx.x, l = tid & 63, w = tid >> 6;   // w: 0..7
    const int lr = l & 15, lg = l >> 4;
    const int jsub = (w & 3) * 32;       // wave j-offset within 128
    const int isub = (w >> 2) * 64;      // wave i-offset within 128

    const _Float16* qa = qb_ + (size_t)(j0 + jsub + lr) * 64 + lg*8;
    const _Float16* ka = kb_ + (size_t)(i0 + isub + lr) * 64 + lg*8;

    f32x4v acc[2][4] = {};   // [j-group][i-tile]
    #pragma unroll
    for (int d0 = 0; d0 < 2; ++d0) {
        const int dd = d0 * 32;
        const h8 ah0 = *(const h8*)(qa + dd);
        const h8 al0 = *(const h8*)(qa + dd + 65536);
        const h8 ah1 = *(const h8*)(qa + dd + 16*64);
        const h8 al1 = *(const h8*)(qa + dd + 16*64 + 65536);
        #pragma unroll
        for (int itile = 0; itile < 4; ++itile) {
            const h8 bhf = *(const h8*)(ka + dd + itile*16*64);
            const h8 blf = *(const h8*)(ka + dd + itile*16*64 + 65536);
            MM1(acc[0][itile], ah0, al0, bhf, blf)
            MM1(acc[1][itile], ah1, al1, bhf, blf)
        }
    }

    // D[m=j][n=i]: lane -> i = i0+isub+itile*16+lr (fixed), j = j0+jsub+jg*16+lg*4 (contig)
    const int bn = bnum[0];
    const float sc_at = 0.125f * aug_at[bn];
    float local = 0.f;
    #pragma unroll
    for (int itile = 0; itile < 4; ++itile) {
        const int gi = i0 + isub + itile*16 + lr;
        const size_t xrow = ((size_t)b*NS + gi)*NS;     // aux row (per-b)
        const size_t arow = ((size_t)bh*NS + gi)*NS;    // e row (per-bh)
        #pragma unroll
        for (int jg = 0; jg < 2; ++jg) {
            const int gj = j0 + jsub + jg*16 + lg*4;
            const h4 x4 = *(const h4*)(aux + xrow + gj);
            f4 e4;
            e4.x = __expf(fmaf(acc[jg][itile][0], sc_at, (float)x4[0]));
            e4.y = __expf(fmaf(acc[jg][itile][1], sc_at, (float)x4[1]));
            e4.z = __expf(fmaf(acc[jg][itile][2], sc_at, (float)x4[2]));
            e4.w = __expf(fmaf(acc[jg][itile][3], sc_at, (float)x4[3]));
            __builtin_nontemporal_store(e4, (f4*)(attn + arow + gj));
            local += (e4.x + e4.y) + (e4.z + e4.w);
        }
    }
    #pragma unroll
    for (int o = 32; o > 0; o >>= 1) local += __shfl_down(local, o);
    if ((tid & 63) == 0) wred[w] = local;
    __syncthreads();
    if (tid == 0)
        ws[OFF_PART + bh*64 + it*8 + jt_] =
            ((wred[0] + wred[1]) + (wred[2] + wred[3])) +
            ((wred[4] + wred[5]) + (wred[6] + wred[7]));
}

// ---------------- k_pv: inv-reduce + nt-read e, nt-write attn=e*inv, ctx_partial=(e*inv)@V
__global__ __launch_bounds__(256, 4) void k_pv(
    float* __restrict__ ws, float* __restrict__ attn)
{
    __shared__ float Es[64][68];    // [j][i], ESW-swizzled
    __shared__ float Vs[64][68];    // [j][d]
    __shared__ float s_inv;
    const int F = blockIdx.x + (blockIdx.y << 1) + (blockIdx.z << 5);  // 0..1023
    const int r = F & 7, s = F >> 3;
    const int bh = (r << 2) | (s & 3);
    const int w = s >> 2;
    const int i0 = (w >> 1) * 64;
    const int jh = w & 1;
    const int b = bh >> 3, h = bh & 7;
    const float* vh = ws + OFF_VH + (size_t)bh*NS*DEPTH;
    float* pctx = ws + (jh ? OFF_CTX1 : OFF_CTX0);
    const int tid = threadIdx.x, tx = tid & 15, ty = tid >> 4;
    const int er_ = tid >> 4, ec4 = tid & 15;

    if (tid < 64) {
        float vsum = ws[OFF_PART + bh*64 + tid];
        #pragma unroll
        for (int o = 32; o > 0; o >>= 1) vsum += __shfl_down(vsum, o);
        if (tid == 0) s_inv = 1.0f / vsum;
    }
    __syncthreads();
    const float inv = s_inv;

    float acc[4][4] = {};
    for (int jt = 0; jt < 8; ++jt) {
        const int j0 = jh*512 + jt*64;
        #pragma unroll
        for (int l = 0; l < 4; ++l) {
            const int rr = er_ + l*16;
            float* ap = attn + ((size_t)bh*NS + i0 + rr)*NS + j0 + ec4*4;
            f4 e4 = __builtin_nontemporal_load((const f4*)ap);
            e4 *= inv;
            __builtin_nontemporal_store(e4, (f4*)ap);
            Es[ec4*4+0][ESW(ec4*4+0, rr)] = e4.x;
            Es[ec4*4+1][ESW(ec4*4+1, rr)] = e4.y;
            Es[ec4*4+2][ESW(ec4*4+2, rr)] = e4.z;
            Es[ec4*4+3][ESW(ec4*4+3, rr)] = e4.w;
            *(float4*)&Vs[rr][ec4*4] = *(const float4*)(vh + (size_t)(j0+rr)*DEPTH + ec4*4);
        }
        __syncthreads();
        #pragma unroll
        for (int jj = 0; jj < 64; ++jj) {
            const float4 a  = *(const float4*)&Es[jj][ESW(jj, ty*4)];
            const float4 vv = *(const float4*)&Vs[jj][tx*4];
            const float av[4] = {a.x,a.y,a.z,a.w};
            const float vw[4] = {vv.x,vv.y,vv.z,vv.w};
            #pragma unroll
            for (int i = 0; i < 4; ++i)
                #pragma unroll
                for (int d = 0; d < 4; ++d)
                    acc[i][d] = fmaf(av[i], vw[d], acc[i][d]);
        }
        __syncthreads();
    }
    #pragma unroll
    for (int i = 0; i < 4; ++i) {
        const int gi = i0 + ty*4 + i;
        float4 o;
        o.x = acc[i][0]; o.y = acc[i][1]; o.z = acc[i][2]; o.w = acc[i][3];
        *(float4*)(pctx + ((size_t)b*NS + gi)*DM + h*DEPTH + tx*4) = o;
    }
}

// ---------------- out = (ctx0+ctx1) @ wo + b via fp16-split MFMA (ctx pre-scaled)
__global__ __launch_bounds__(256, 3) void k_out(
    const float* __restrict__ wsc, const float* __restrict__ bo,
    float* __restrict__ outp)
{
    const int f = blockIdx.x + (blockIdx.y << 3);       // grid MUST be (8,32)
    const int n0 = (f >> 5) * 64, m0 = (f & 31) * 128;
    const int tid = threadIdx.x, l = tid & 63, w = tid >> 6;
    const int lr = l & 15, lg = l >> 4;

    const _Float16* whi = (const _Float16*)(wsc + OFF_VH);
    const _Float16* wlo = whi + 262144;
    const float* ap0 = wsc + OFF_CTX0 + (size_t)(m0 + w*32 + lr) * DM + lg*8;
    const float* ap1 = wsc + OFF_CTX1 + (size_t)(m0 + w*32 + lr) * DM + lg*8;
    const _Float16* bh_base = whi + (size_t)(n0 >> 4) * 8192 + lg*128 + lr*8;
    const _Float16* bl_base = wlo + (size_t)(n0 >> 4) * 8192 + lg*128 + lr*8;

    f32x4v aH00 = 0, aH01 = 0, aH02 = 0, aH03 = 0;
    f32x4v aH10 = 0, aH11 = 0, aH12 = 0, aH13 = 0;
    f32x4v aM00 = 0, aM01 = 0, aM02 = 0, aM03 = 0;
    f32x4v aM10 = 0, aM11 = 0, aM12 = 0, aM13 = 0;

    #pragma unroll 1
    for (int kb = 0; kb < DM; kb += 32) {
        h8 ah0, al0, ah1, al1;
        {
            float4 u0 = *(const float4*)(ap0 + kb);
            float4 u1 = *(const float4*)(ap0 + kb + 4);
            const float4 c0 = *(const float4*)(ap1 + kb);
            const float4 c1 = *(const float4*)(ap1 + kb + 4);
            u0.x=(u0.x+c0.x)*ASCALE; u0.y=(u0.y+c0.y)*ASCALE;
            u0.z=(u0.z+c0.z)*ASCALE; u0.w=(u0.w+c0.w)*ASCALE;
            u1.x=(u1.x+c1.x)*ASCALE; u1.y=(u1.y+c1.y)*ASCALE;
            u1.z=(u1.z+c1.z)*ASCALE; u1.w=(u1.w+c1.w)*ASCALE;
            SPLIT8(u0, u1, ah0, al0);
            float4 v0 = *(const float4*)(ap0 + (size_t)16*DM + kb);
            float4 v1 = *(const float4*)(ap0 + (size_t)16*DM + kb + 4);
            const float4 d0 = *(const float4*)(ap1 + (size_t)16*DM + kb);
            const float4 d1 = *(const float4*)(ap1 + (size_t)16*DM + kb + 4);
            v0.x=(v0.x+d0.x)*ASCALE; v0.y=(v0.y+d0.y)*ASCALE;
            v0.z=(v0.z+d0.z)*ASCALE; v0.w=(v0.w+d0.w)*ASCALE;
            v1.x=(v1.x+d1.x)*ASCALE; v1.y=(v1.y+d1.y)*ASCALE;
            v1.z=(v1.z+d1.z)*ASCALE; v1.w=(v1.w+d1.w)*ASCALE;
            SPLIT8(v0, v1, ah1, al1);
        }
        const int boff = kb * 16;
        const h8 bh0 = *(const h8*)(bh_base + boff);
        const h8 bh1 = *(const h8*)(bh_base + boff + 8192);
        const h8 bh2 = *(const h8*)(bh_base + boff + 16384);
        const h8 bh3 = *(const h8*)(bh_base + boff + 24576);
        const h8 bl0 = *(const h8*)(bl_base + boff);
        const h8 bl1 = *(const h8*)(bl_base + boff + 8192);
        const h8 bl2 = *(const h8*)(bl_base + boff + 16384);
        const h8 bl3 = *(const h8*)(bl_base + boff + 24576);

        MM(aH00, aM00, ah0, al0, bh0, bl0) MM(aH01, aM01, ah0, al0, bh1, bl1)
        MM(aH02, aM02, ah0, al0, bh2, bl2) MM(aH03, aM03, ah0, al0, bh3, bl3)
        MM(aH10, aM10, ah1, al1, bh0, bl0) MM(aH11, aM11, ah1, al1, bh1, bl1)
        MM(aH12, aM12, ah1, al1, bh2, bl2) MM(aH13, aM13, ah1, al1, bh3, bl3)
    }

    #define STORE_TILE(accH, accM, nt, mt) {                                 \
        const int n = n0 + (nt)*16 + lr;                                     \
        const float bsv = bo[n];                                             \
        const int mbase = m0 + w*32 + (mt)*16 + lg*4;                        \
        _Pragma("unroll")                                                    \
        for (int r = 0; r < 4; ++r)                                          \
            outp[(size_t)(mbase + r)*DM + n] =                               \
                fmaf(accM[r], LO_INV, accH[r]) * AUNSCALE + bsv;             \
    }
    STORE_TILE(aH00, aM00, 0, 0) STORE_TILE(aH10, aM10, 0, 1)
    STORE_TILE(aH01, aM01, 1, 0) STORE_TILE(aH11, aM11, 1, 1)
    STORE_TILE(aH02, aM02, 2, 0) STORE_TILE(aH12, aM12, 2, 1)
    STORE_TILE(aH03, aM03, 3, 0) STORE_TILE(aH13, aM13, 3, 1)
    #undef STORE_TILE
}

extern "C" void kernel_launch(void* const* d_in, const int* in_sizes, int n_in,
                              void* d_out, int out_size, void* d_ws, size_t ws_size,
                              hipStream_t stream)
{
    const float* v    = (const float*)d_in[0];
    const float* q    = (const float*)d_in[1];
    const float* k    = (const float*)d_in[2];
    const float* wq_w = (const float*)d_in[3];
    const float* wq_b = (const float*)d_in[4];
    const float* wk_w = (const float*)d_in[5];
    const float* wk_b = (const float*)d_in[6];
    const float* wv_w = (const float*)d_in[7];
    const float* wv_b = (const float*)d_in[8];
    const float* wo_w = (const float*)d_in[9];
    const float* wo_b = (const float*)d_in[10];
    const float* aug_hb = (const float*)d_in[11];
    const float* aug_pi = (const float*)d_in[12];
    const float* aug_at = (const float*)d_in[13];
    const float* t_hb   = (const float*)d_in[14];
    const float* t_pi   = (const float*)d_in[15];
    const float* mask   = (const float*)d_in[16];
    const int*   bnum   = (const int*)d_in[17];

    float* ws   = (float*)d_ws;
    float* outp = (float*)d_out;
    float* attn = (float*)d_out + (size_t)4*NS*DM;

    // 1. wq/wk/wv bricks into d_out attn region (overwritten later by k_score)
    hipLaunchKernelGGL(k_prep_qkv, dim3(256, 3), dim3(256), 0, stream,
                       wq_w, wk_w, wv_w, attn);
    // 1b. aux f16 plane (mask+tables folded) into d_out out region (dead until k_out)
    hipLaunchKernelGGL(k_prep_aux, dim3(4096), dim3(256), 0, stream,
                       mask, t_hb, t_pi, aug_hb, aug_pi, aug_at, bnum, outp);
    // 2. projections (MFMA); q/k -> f16 hi/lo planes, v -> fp32
    hipLaunchKernelGGL(k_proj, dim3(8, 32, 3), dim3(256), 0, stream,
                       q, k, v, wq_b, wk_b, wv_b, ws, attn);
    // 3. scores via MFMA + e + partial sums (reads aux; 512-thread blocks now)
    hipLaunchKernelGGL(k_score, dim3(8, 8, 32), dim3(512), 0, stream,
                       ws, (const _Float16*)outp, aug_at, bnum, attn);
    // 4. PV + attn normalization (VH dead afterwards)
    hipLaunchKernelGGL(k_pv, dim3(2, 16, 32), dim3(256), 0, stream, ws, attn);
    // 5. wo bricks into the now-dead VH region
    hipLaunchKernelGGL(k_prep_wo, dim3(256, 1), dim3(256), 0, stream, wo_w, ws);
    // 6. output projection (MFMA), grid (8,32) = 256 blocks exactly; overwrites aux
    hipLaunchKernelGGL(k_out, dim3(8, 32), dim3(256), 0, stream,
                       ws, wo_b, outp);
}

// Round 17
// 222.776 us; speedup vs baseline: 1.1070x; 1.1070x over previous
//
#include <hip/hip_runtime.h>
#include <math.h>

#define NS 1024
#define DM 512
#define NH 8
#define DEPTH 64

// ws offsets (floats). Lifetimes:
//  QH/KH: f16 hi+lo qh/kh (k_proj -> k_score) -> reused as CTX0/CTX1 (k_pv/k_out).
//  VH: fp32 vh (k_proj -> k_pv), then wo bricks (k_prep_wo -> k_out).
// aux f16 plane (8MB) lives in d_out's out region (dead until k_out).
#define OFF_QH   0
#define OFF_KH   2097152
#define OFF_VH   4194304
#define OFF_CTX0 0
#define OFF_CTX1 2097152
#define OFF_PART 6291456

#define ESW(row, col) ((col) ^ ((((row) >> 3) & 7) << 2))   // rows 0..63 scatter

#define LO_SCALE 2048.0f
#define LO_INV   (1.0f/2048.0f)
#define F16_MIN_NORM 6.1035156e-5f
#define ASCALE   4096.0f
#define AUNSCALE (1.0f/4096.0f)

typedef float f4 __attribute__((ext_vector_type(4)));
typedef _Float16 h8 __attribute__((ext_vector_type(8)));
typedef _Float16 h4 __attribute__((ext_vector_type(4)));
typedef float f32x4v __attribute__((ext_vector_type(4)));

// guarded hi + scaled lo (for small-magnitude data: weights, ctx)
#define SPLIT1(x, hi_e, lo_e) {                                          \
    const float x_ = (x);                                                \
    _Float16 t = (fabsf(x_) >= F16_MIN_NORM) ? (_Float16)x_ : (_Float16)0.f; \
    hi_e = t;                                                            \
    lo_e = (_Float16)((x_ - (float)t) * LO_SCALE);                       \
}

#define SPLIT8(u0, u1, hi, lo) {                                         \
    SPLIT1(u0.x, hi[0], lo[0]) SPLIT1(u0.y, hi[1], lo[1])                \
    SPLIT1(u0.z, hi[2], lo[2]) SPLIT1(u0.w, hi[3], lo[3])                \
    SPLIT1(u1.x, hi[4], lo[4]) SPLIT1(u1.y, hi[5], lo[5])                \
    SPLIT1(u1.z, hi[6], lo[6]) SPLIT1(u1.w, hi[7], lo[7])                \
}

// 3-MFMA scaled split product (separate accM, for LO_SCALE'd operands)
#define MM(accH, accM, a_h, a_l, b_h, b_l) {                                   \
    accH = __builtin_amdgcn_mfma_f32_16x16x32_f16(a_h, b_h, accH, 0, 0, 0);    \
    accM = __builtin_amdgcn_mfma_f32_16x16x32_f16(a_l, b_h, accM, 0, 0, 0);    \
    accM = __builtin_amdgcn_mfma_f32_16x16x32_f16(a_h, b_l, accM, 0, 0, 0);    \
}
// 3-MFMA unscaled split product (O(1) data: lo is fp16-normal, one acc)
#define MM1(acc, a_h, a_l, b_h, b_l) {                                         \
    acc = __builtin_amdgcn_mfma_f32_16x16x32_f16(a_h, b_h, acc, 0, 0, 0);      \
    acc = __builtin_amdgcn_mfma_f32_16x16x32_f16(a_l, b_h, acc, 0, 0, 0);      \
    acc = __builtin_amdgcn_mfma_f32_16x16x32_f16(a_h, b_l, acc, 0, 0, 0);      \
}

// ---- prep body: W fp32 -> fp16 hi + scaled-lo bricks (262144 halves each)
__device__ __forceinline__ void prep_one(
    const float* __restrict__ W, _Float16* __restrict__ whi,
    _Float16* __restrict__ wlo, int g)
{
    const int kk = g >> 7;
    const int n  = (g & 127) * 4;
    const float4 f = *(const float4*)(W + (size_t)kk * DM + n);
    const int gbase = (kk >> 3) * 128 + (kk & 7);
    #define PREP1(val, nn) {                                             \
        const int a_ = ((nn) >> 4) * 8192 + gbase + ((nn) & 15) * 8;     \
        _Float16 h_; _Float16 l_;                                        \
        SPLIT1(val, h_, l_)                                              \
        whi[a_] = h_; wlo[a_] = l_;                                      \
    }
    PREP1(f.x, n + 0) PREP1(f.y, n + 1) PREP1(f.z, n + 2) PREP1(f.w, n + 3)
    #undef PREP1
}

__global__ __launch_bounds__(256) void k_prep_qkv(
    const float* __restrict__ wq, const float* __restrict__ wk,
    const float* __restrict__ wv, float* __restrict__ attn)
{
    const int w = blockIdx.y;
    const float* W = (w == 0) ? wq : (w == 1) ? wk : wv;
    _Float16* base = (_Float16*)attn + (size_t)w * 524288;
    prep_one(W, base, base + 262144, blockIdx.x * 256 + threadIdx.x);
}

__global__ __launch_bounds__(256) void k_prep_wo(
    const float* __restrict__ wo, float* __restrict__ ws)
{
    _Float16* base = (_Float16*)(ws + OFF_VH);
    prep_one(wo, base, base + 262144, blockIdx.x * 256 + threadIdx.x);
}

// ---- aux fold: aux[b][i][j] = f16( mask*(-1e9*at) + hb*t_hb + pi*t_pi ), clamped.
// Written into d_out's out region (8MB, dead until k_out).
__global__ __launch_bounds__(256) void k_prep_aux(
    const float* __restrict__ mask, const float* __restrict__ t_hb,
    const float* __restrict__ t_pi,
    const float* __restrict__ aug_hb, const float* __restrict__ aug_pi,
    const float* __restrict__ aug_at, const int* __restrict__ bnum,
    float* __restrict__ outp)
{
    const int g = blockIdx.x * 256 + threadIdx.x;       // 0..1M-1
    const size_t e0 = (size_t)g * 4;
    const size_t t0 = e0 & (size_t)(NS*NS - 1);
    const int bn = bnum[0];
    const float at = aug_at[bn], hb = aug_hb[bn], pi = aug_pi[bn];
    const float m_at = -1e9f * at;
    const f4 m4 = *(const f4*)(mask + e0);
    const f4 th = *(const f4*)(t_hb + t0);
    const f4 tp = *(const f4*)(t_pi + t0);
    h4 o;
    float a;
    a = fmaf(m4.x, m_at, fmaf(hb, th.x, pi*tp.x)); if (a < -60000.f) a = -60000.f; o[0] = (_Float16)a;
    a = fmaf(m4.y, m_at, fmaf(hb, th.y, pi*tp.y)); if (a < -60000.f) a = -60000.f; o[1] = (_Float16)a;
    a = fmaf(m4.z, m_at, fmaf(hb, th.z, pi*tp.z)); if (a < -60000.f) a = -60000.f; o[2] = (_Float16)a;
    a = fmaf(m4.w, m_at, fmaf(hb, th.w, pi*tp.w)); if (a < -60000.f) a = -60000.f; o[3] = (_Float16)a;
    *(h4*)((_Float16*)outp + e0) = o;
}

// ---------------- QKV projection via fp16-split MFMA: X@W+b -> split heads
// q/k results written as f16 hi/lo planes [bh][s][d] (lo at +65536 halves);
// v written fp32 (k_pv consumes it).
__global__ __launch_bounds__(256, 3) void k_proj(
    const float* __restrict__ q, const float* __restrict__ k, const float* __restrict__ v,
    const float* __restrict__ bq, const float* __restrict__ bk, const float* __restrict__ bv,
    float* __restrict__ ws, const float* __restrict__ attn)
{
    const float *X, *bias; int wsel;
    if (blockIdx.z == 0)      { X=q; bias=bq; wsel=0; }
    else if (blockIdx.z == 1) { X=k; bias=bk; wsel=1; }
    else                      { X=v; bias=bv; wsel=2; }
    float* outf = ws + OFF_VH;                       // v only
    _Float16* outh = (_Float16*)(ws + (wsel == 0 ? OFF_QH : OFF_KH));  // q/k

    const int f = blockIdx.x + (blockIdx.y << 3);       // 0..255
    const int n0 = (f >> 5) * 64, m0 = (f & 31) * 128;
    const int tid = threadIdx.x, l = tid & 63, w = tid >> 6;
    const int lr = l & 15, lg = l >> 4;

    const _Float16* whi = (const _Float16*)attn + (size_t)wsel * 524288;
    const _Float16* wlo = whi + 262144;
    const float* ap0 = X + (size_t)(m0 + w*32 + lr) * DM + lg*8;
    const float* ap1 = ap0 + (size_t)16 * DM;
    const _Float16* bh_base = whi + (size_t)(n0 >> 4) * 8192 + lg*128 + lr*8;
    const _Float16* bl_base = wlo + (size_t)(n0 >> 4) * 8192 + lg*128 + lr*8;

    f32x4v aH00 = 0, aH01 = 0, aH02 = 0, aH03 = 0;
    f32x4v aH10 = 0, aH11 = 0, aH12 = 0, aH13 = 0;
    f32x4v aM00 = 0, aM01 = 0, aM02 = 0, aM03 = 0;
    f32x4v aM10 = 0, aM11 = 0, aM12 = 0, aM13 = 0;

    #pragma unroll 1
    for (int kb = 0; kb < DM; kb += 32) {
        h8 ah0, al0, ah1, al1;
        {
            const float4 u0 = *(const float4*)(ap0 + kb);
            const float4 u1 = *(const float4*)(ap0 + kb + 4);
            SPLIT8(u0, u1, ah0, al0);
            const float4 v0 = *(const float4*)(ap1 + kb);
            const float4 v1 = *(const float4*)(ap1 + kb + 4);
            SPLIT8(v0, v1, ah1, al1);
        }
        const int boff = kb * 16;
        const h8 bh0 = *(const h8*)(bh_base + boff);
        const h8 bh1 = *(const h8*)(bh_base + boff + 8192);
        const h8 bh2 = *(const h8*)(bh_base + boff + 16384);
        const h8 bh3 = *(const h8*)(bh_base + boff + 24576);
        const h8 bl0 = *(const h8*)(bl_base + boff);
        const h8 bl1 = *(const h8*)(bl_base + boff + 8192);
        const h8 bl2 = *(const h8*)(bl_base + boff + 16384);
        const h8 bl3 = *(const h8*)(bl_base + boff + 24576);

        MM(aH00, aM00, ah0, al0, bh0, bl0) MM(aH01, aM01, ah0, al0, bh1, bl1)
        MM(aH02, aM02, ah0, al0, bh2, bl2) MM(aH03, aM03, ah0, al0, bh3, bl3)
        MM(aH10, aM10, ah1, al1, bh0, bl0) MM(aH11, aM11, ah1, al1, bh1, bl1)
        MM(aH12, aM12, ah1, al1, bh2, bl2) MM(aH13, aM13, ah1, al1, bh3, bl3)
    }

    const int h = n0 >> 6;
    #define STORE_TILE(accH, accM, nt, mt) {                                 \
        const int n = n0 + (nt)*16 + lr;                                     \
        const float bsv = bias[n];                                           \
        const int d = n & 63;                                                \
        const int mbase = m0 + w*32 + (mt)*16 + lg*4;                        \
        _Pragma("unroll")                                                    \
        for (int r = 0; r < 4; ++r) {                                        \
            const int m = mbase + r;                                         \
            const int bb = m >> 10, s = m & 1023;                            \
            const float val = fmaf(accM[r], LO_INV, accH[r]) + bsv;          \
            if (wsel == 2) {                                                 \
                outf[(((size_t)(bb*NH + h))*NS + s)*DEPTH + d] = val;        \
            } else {                                                         \
                _Float16* p = outh + (size_t)(bb*NH + h)*131072              \
                                   + (size_t)s*64 + d;                       \
                const _Float16 hi_ = (_Float16)val;                          \
                p[0]     = hi_;                                              \
                p[65536] = (_Float16)(val - (float)hi_);                     \
            }                                                                \
        }                                                                    \
    }
    STORE_TILE(aH00, aM00, 0, 0) STORE_TILE(aH10, aM10, 0, 1)
    STORE_TILE(aH01, aM01, 1, 0) STORE_TILE(aH11, aM11, 1, 1)
    STORE_TILE(aH02, aM02, 2, 0) STORE_TILE(aH12, aM12, 2, 1)
    STORE_TILE(aH03, aM03, 3, 0) STORE_TILE(aH13, aM13, 3, 1)
    #undef STORE_TILE
}

// ---------------- k_score: S = K.Q^T via MFMA (R12 orientation: A=K rows i, B=Q rows j)
// e = exp(acc*sc_at + aux) -> plain (cached) scalar store + partial sums.
// 128x128 tile, 4 waves x (32i x 128j), no LDS, no K-loop barriers.
__global__ __launch_bounds__(256, 3) void k_score(
    float* __restrict__ ws,
    const _Float16* __restrict__ aux,
    const float* __restrict__ aug_at, const int* __restrict__ bnum,
    float* __restrict__ attn)
{
    __shared__ float wred[4];
    const int bh = blockIdx.z, b = bh >> 3;
    const int f = blockIdx.x + (blockIdx.y << 3);  // 0..63, rect XCD grouping
    const int r = f & 7, qq = f >> 3;
    const int it = ((r & 1) << 2) | (qq & 3);
    const int jt_ = ((r >> 1) << 1) | (qq >> 2);
    const int i0 = it * 128, j0 = jt_ * 128;
    const _Float16* kb_ = (const _Float16*)(ws + OFF_KH) + (size_t)bh * 131072;
    const _Float16* qb_ = (const _Float16*)(ws + OFF_QH) + (size_t)bh * 131072;
    const int tid = threadIdx.x, l = tid & 63, w = tid >> 6;
    const int lr = l & 15, lg = l >> 4;

    // wave w covers i-rows [i0 + w*32, +32) x all 128 j
    const _Float16* ka = kb_ + (size_t)(i0 + w*32 + lr) * 64 + lg*8;
    const _Float16* qa = qb_ + (size_t)(j0 + lr) * 64 + lg*8;

    f32x4v acc[2][8] = {};
    #pragma unroll
    for (int d0 = 0; d0 < 2; ++d0) {
        const int dd = d0 * 32;
        const h8 ah0 = *(const h8*)(ka + dd);
        const h8 al0 = *(const h8*)(ka + dd + 65536);
        const h8 ah1 = *(const h8*)(ka + dd + 16*64);
        const h8 al1 = *(const h8*)(ka + dd + 16*64 + 65536);
        #pragma unroll
        for (int jt = 0; jt < 8; ++jt) {
            const h8 bhf = *(const h8*)(qa + dd + jt*16*64);
            const h8 blf = *(const h8*)(qa + dd + jt*16*64 + 65536);
            MM1(acc[0][jt], ah0, al0, bhf, blf)
            MM1(acc[1][jt], ah1, al1, bhf, blf)
        }
    }

    // D[m=i][n=j]: lane holds i = i0+w*32+it2*16+lg*4+reg, j = j0+jt*16+lr (fixed)
    const int bn = bnum[0];
    const float sc_at = 0.125f * aug_at[bn];
    float local = 0.f;
    #pragma unroll
    for (int it2 = 0; it2 < 2; ++it2) {
        #pragma unroll
        for (int rr = 0; rr < 4; ++rr) {
            const int gi = i0 + w*32 + it2*16 + lg*4 + rr;
            const size_t xrow = ((size_t)b*NS + gi)*NS;
            const size_t arow = ((size_t)bh*NS + gi)*NS;
            #pragma unroll
            for (int jt = 0; jt < 8; ++jt) {
                const int gj = j0 + jt*16 + lr;
                const float xv = (float)aux[xrow + gj];
                const float e = __expf(fmaf(acc[it2][jt][rr], sc_at, xv));
                attn[arow + gj] = e;            // plain cached store (stays in L2/L3 for k_pv)
                local += e;
            }
        }
    }
    #pragma unroll
    for (int o = 32; o > 0; o >>= 1) local += __shfl_down(local, o);
    if ((tid & 63) == 0) wred[tid >> 6] = local;
    __syncthreads();
    if (tid == 0)
        ws[OFF_PART + bh*64 + it*8 + jt_] =
            (wred[0] + wred[1]) + (wred[2] + wred[3]);
}

// ---------------- k_pv: inv-reduce + read e (cached), write attn=e*inv, ctx_partial=(e*inv)@V
__global__ __launch_bounds__(256, 4) void k_pv(
    float* __restrict__ ws, float* __restrict__ attn)
{
    __shared__ float Es[64][68];    // [j][i], ESW-swizzled
    __shared__ float Vs[64][68];    // [j][d]
    __shared__ float s_inv;
    const int F = blockIdx.x + (blockIdx.y << 1) + (blockIdx.z << 5);  // 0..1023
    const int r = F & 7, s = F >> 3;
    const int bh = (r << 2) | (s & 3);
    const int w = s >> 2;
    const int i0 = (w >> 1) * 64;
    const int jh = w & 1;
    const int b = bh >> 3, h = bh & 7;
    const float* vh = ws + OFF_VH + (size_t)bh*NS*DEPTH;
    float* pctx = ws + (jh ? OFF_CTX1 : OFF_CTX0);
    const int tid = threadIdx.x, tx = tid & 15, ty = tid >> 4;
    const int er_ = tid >> 4, ec4 = tid & 15;

    if (tid < 64) {
        float vsum = ws[OFF_PART + bh*64 + tid];
        #pragma unroll
        for (int o = 32; o > 0; o >>= 1) vsum += __shfl_down(vsum, o);
        if (tid == 0) s_inv = 1.0f / vsum;
    }
    __syncthreads();
    const float inv = s_inv;

    float acc[4][4] = {};
    for (int jt = 0; jt < 8; ++jt) {
        const int j0 = jh*512 + jt*64;
        #pragma unroll
        for (int l = 0; l < 4; ++l) {
            const int rr = er_ + l*16;
            float* ap = attn + ((size_t)bh*NS + i0 + rr)*NS + j0 + ec4*4;
            f4 e4 = *(const f4*)ap;
            e4 *= inv;
            *(f4*)ap = e4;                     // final normalized attn
            Es[ec4*4+0][ESW(ec4*4+0, rr)] = e4.x;
            Es[ec4*4+1][ESW(ec4*4+1, rr)] = e4.y;
            Es[ec4*4+2][ESW(ec4*4+2, rr)] = e4.z;
            Es[ec4*4+3][ESW(ec4*4+3, rr)] = e4.w;
            *(float4*)&Vs[rr][ec4*4] = *(const float4*)(vh + (size_t)(j0+rr)*DEPTH + ec4*4);
        }
        __syncthreads();
        #pragma unroll
        for (int jj = 0; jj < 64; ++jj) {
            const float4 a  = *(const float4*)&Es[jj][ESW(jj, ty*4)];
            const float4 vv = *(const float4*)&Vs[jj][tx*4];
            const float av[4] = {a.x,a.y,a.z,a.w};
            const float vw[4] = {vv.x,vv.y,vv.z,vv.w};
            #pragma unroll
            for (int i = 0; i < 4; ++i)
                #pragma unroll
                for (int d = 0; d < 4; ++d)
                    acc[i][d] = fmaf(av[i], vw[d], acc[i][d]);
        }
        __syncthreads();
    }
    #pragma unroll
    for (int i = 0; i < 4; ++i) {
        const int gi = i0 + ty*4 + i;
        float4 o;
        o.x = acc[i][0]; o.y = acc[i][1]; o.z = acc[i][2]; o.w = acc[i][3];
        *(float4*)(pctx + ((size_t)b*NS + gi)*DM + h*DEPTH + tx*4) = o;
    }
}

// ---------------- out = (ctx0+ctx1) @ wo + b via fp16-split MFMA (ctx pre-scaled)
__global__ __launch_bounds__(256, 3) void k_out(
    const float* __restrict__ wsc, const float* __restrict__ bo,
    float* __restrict__ outp)
{
    const int f = blockIdx.x + (blockIdx.y << 3);       // grid MUST be (8,32)
    const int n0 = (f >> 5) * 64, m0 = (f & 31) * 128;
    const int tid = threadIdx.x, l = tid & 63, w = tid >> 6;
    const int lr = l & 15, lg = l >> 4;

    const _Float16* whi = (const _Float16*)(wsc + OFF_VH);
    const _Float16* wlo = whi + 262144;
    const float* ap0 = wsc + OFF_CTX0 + (size_t)(m0 + w*32 + lr) * DM + lg*8;
    const float* ap1 = wsc + OFF_CTX1 + (size_t)(m0 + w*32 + lr) * DM + lg*8;
    const _Float16* bh_base = whi + (size_t)(n0 >> 4) * 8192 + lg*128 + lr*8;
    const _Float16* bl_base = wlo + (size_t)(n0 >> 4) * 8192 + lg*128 + lr*8;

    f32x4v aH00 = 0, aH01 = 0, aH02 = 0, aH03 = 0;
    f32x4v aH10 = 0, aH11 = 0, aH12 = 0, aH13 = 0;
    f32x4v aM00 = 0, aM01 = 0, aM02 = 0, aM03 = 0;
    f32x4v aM10 = 0, aM11 = 0, aM12 = 0, aM13 = 0;

    #pragma unroll 1
    for (int kb = 0; kb < DM; kb += 32) {
        h8 ah0, al0, ah1, al1;
        {
            float4 u0 = *(const float4*)(ap0 + kb);
            float4 u1 = *(const float4*)(ap0 + kb + 4);
            const float4 c0 = *(const float4*)(ap1 + kb);
            const float4 c1 = *(const float4*)(ap1 + kb + 4);
            u0.x=(u0.x+c0.x)*ASCALE; u0.y=(u0.y+c0.y)*ASCALE;
            u0.z=(u0.z+c0.z)*ASCALE; u0.w=(u0.w+c0.w)*ASCALE;
            u1.x=(u1.x+c1.x)*ASCALE; u1.y=(u1.y+c1.y)*ASCALE;
            u1.z=(u1.z+c1.z)*ASCALE; u1.w=(u1.w+c1.w)*ASCALE;
            SPLIT8(u0, u1, ah0, al0);
            float4 v0 = *(const float4*)(ap0 + (size_t)16*DM + kb);
            float4 v1 = *(const float4*)(ap0 + (size_t)16*DM + kb + 4);
            const float4 d0 = *(const float4*)(ap1 + (size_t)16*DM + kb);
            const float4 d1 = *(const float4*)(ap1 + (size_t)16*DM + kb + 4);
            v0.x=(v0.x+d0.x)*ASCALE; v0.y=(v0.y+d0.y)*ASCALE;
            v0.z=(v0.z+d0.z)*ASCALE; v0.w=(v0.w+d0.w)*ASCALE;
            v1.x=(v1.x+d1.x)*ASCALE; v1.y=(v1.y+d1.y)*ASCALE;
            v1.z=(v1.z+d1.z)*ASCALE; v1.w=(v1.w+d1.w)*ASCALE;
            SPLIT8(v0, v1, ah1, al1);
        }
        const int boff = kb * 16;
        const h8 bh0 = *(const h8*)(bh_base + boff);
        const h8 bh1 = *(const h8*)(bh_base + boff + 8192);
        const h8 bh2 = *(const h8*)(bh_base + boff + 16384);
        const h8 bh3 = *(const h8*)(bh_base + boff + 24576);
        const h8 bl0 = *(const h8*)(bl_base + boff);
        const h8 bl1 = *(const h8*)(bl_base + boff + 8192);
        const h8 bl2 = *(const h8*)(bl_base + boff + 16384);
        const h8 bl3 = *(const h8*)(bl_base + boff + 24576);

        MM(aH00, aM00, ah0, al0, bh0, bl0) MM(aH01, aM01, ah0, al0, bh1, bl1)
        MM(aH02, aM02, ah0, al0, bh2, bl2) MM(aH03, aM03, ah0, al0, bh3, bl3)
        MM(aH10, aM10, ah1, al1, bh0, bl0) MM(aH11, aM11, ah1, al1, bh1, bl1)
        MM(aH12, aM12, ah1, al1, bh2, bl2) MM(aH13, aM13, ah1, al1, bh3, bl3)
    }

    #define STORE_TILE(accH, accM, nt, mt) {                                 \
        const int n = n0 + (nt)*16 + lr;                                     \
        const float bsv = bo[n];                                             \
        const int mbase = m0 + w*32 + (mt)*16 + lg*4;                        \
        _Pragma("unroll")                                                    \
        for (int r = 0; r < 4; ++r)                                          \
            outp[(size_t)(mbase + r)*DM + n] =                               \
                fmaf(accM[r], LO_INV, accH[r]) * AUNSCALE + bsv;             \
    }
    STORE_TILE(aH00, aM00, 0, 0) STORE_TILE(aH10, aM10, 0, 1)
    STORE_TILE(aH01, aM01, 1, 0) STORE_TILE(aH11, aM11, 1, 1)
    STORE_TILE(aH02, aM02, 2, 0) STORE_TILE(aH12, aM12, 2, 1)
    STORE_TILE(aH03, aM03, 3, 0) STORE_TILE(aH13, aM13, 3, 1)
    #undef STORE_TILE
}

extern "C" void kernel_launch(void* const* d_in, const int* in_sizes, int n_in,
                              void* d_out, int out_size, void* d_ws, size_t ws_size,
                              hipStream_t stream)
{
    const float* v    = (const float*)d_in[0];
    const float* q    = (const float*)d_in[1];
    const float* k    = (const float*)d_in[2];
    const float* wq_w = (const float*)d_in[3];
    const float* wq_b = (const float*)d_in[4];
    const float* wk_w = (const float*)d_in[5];
    const float* wk_b = (const float*)d_in[6];
    const float* wv_w = (const float*)d_in[7];
    const float* wv_b = (const float*)d_in[8];
    const float* wo_w = (const float*)d_in[9];
    const float* wo_b = (const float*)d_in[10];
    const float* aug_hb = (const float*)d_in[11];
    const float* aug_pi = (const float*)d_in[12];
    const float* aug_at = (const float*)d_in[13];
    const float* t_hb   = (const float*)d_in[14];
    const float* t_pi   = (const float*)d_in[15];
    const float* mask   = (const float*)d_in[16];
    const int*   bnum   = (const int*)d_in[17];

    float* ws   = (float*)d_ws;
    float* outp = (float*)d_out;
    float* attn = (float*)d_out + (size_t)4*NS*DM;

    // 1. wq/wk/wv bricks into d_out attn region (overwritten later by k_score)
    hipLaunchKernelGGL(k_prep_qkv, dim3(256, 3), dim3(256), 0, stream,
                       wq_w, wk_w, wv_w, attn);
    // 1b. aux f16 plane (mask+tables folded) into d_out out region (dead until k_out)
    hipLaunchKernelGGL(k_prep_aux, dim3(4096), dim3(256), 0, stream,
                       mask, t_hb, t_pi, aug_hb, aug_pi, aug_at, bnum, outp);
    // 2. projections (MFMA); q/k -> f16 hi/lo planes, v -> fp32
    hipLaunchKernelGGL(k_proj, dim3(8, 32, 3), dim3(256), 0, stream,
                       q, k, v, wq_b, wk_b, wv_b, ws, attn);
    // 3. scores via MFMA + e + partial sums (reads aux; R12 orientation, cached stores)
    hipLaunchKernelGGL(k_score, dim3(8, 8, 32), dim3(256), 0, stream,
                       ws, (const _Float16*)outp, aug_at, bnum, attn);
    // 4. PV + attn normalization (VH dead afterwards)
    hipLaunchKernelGGL(k_pv, dim3(2, 16, 32), dim3(256), 0, stream, ws, attn);
    // 5. wo bricks into the now-dead VH region
    hipLaunchKernelGGL(k_prep_wo, dim3(256, 1), dim3(256), 0, stream, wo_w, ws);
    // 6. output projection (MFMA), grid (8,32) = 256 blocks exactly; overwrites aux
    hipLaunchKernelGGL(k_out, dim3(8, 32), dim3(256), 0, stream,
                       ws, wo_b, outp);
}

// Round 18
// 222.200 us; speedup vs baseline: 1.1098x; 1.0026x over previous
//
#include <hip/hip_runtime.h>
#include <math.h>

#define NS 1024
#define DM 512
#define NH 8
#define DEPTH 64

// ws offsets (floats). Lifetimes:
//  QH/KH: f16 hi+lo qh/kh (k_proj -> k_score) -> reused as CTX0/CTX1 (k_pv/k_out).
//  VH: fp32 vh (k_proj -> k_pv), then wo bricks (k_prep_wo -> k_out).
// aux f16 plane (8MB) lives in d_out's out region (dead until k_out).
#define OFF_QH   0
#define OFF_KH   2097152
#define OFF_VH   4194304
#define OFF_CTX0 0
#define OFF_CTX1 2097152
#define OFF_PART 6291456

#define ESW(row, col) ((col) ^ ((((row) >> 3) & 7) << 2))   // rows 0..63 scatter

#define LO_SCALE 2048.0f
#define LO_INV   (1.0f/2048.0f)
#define F16_MIN_NORM 6.1035156e-5f
#define ASCALE   4096.0f
#define AUNSCALE (1.0f/4096.0f)

typedef float f4 __attribute__((ext_vector_type(4)));
typedef _Float16 h8 __attribute__((ext_vector_type(8)));
typedef _Float16 h4 __attribute__((ext_vector_type(4)));
typedef float f32x4v __attribute__((ext_vector_type(4)));

// guarded hi + scaled lo (for small-magnitude data: weights, ctx)
#define SPLIT1(x, hi_e, lo_e) {                                          \
    const float x_ = (x);                                                \
    _Float16 t = (fabsf(x_) >= F16_MIN_NORM) ? (_Float16)x_ : (_Float16)0.f; \
    hi_e = t;                                                            \
    lo_e = (_Float16)((x_ - (float)t) * LO_SCALE);                       \
}

#define SPLIT8(u0, u1, hi, lo) {                                         \
    SPLIT1(u0.x, hi[0], lo[0]) SPLIT1(u0.y, hi[1], lo[1])                \
    SPLIT1(u0.z, hi[2], lo[2]) SPLIT1(u0.w, hi[3], lo[3])                \
    SPLIT1(u1.x, hi[4], lo[4]) SPLIT1(u1.y, hi[5], lo[5])                \
    SPLIT1(u1.z, hi[6], lo[6]) SPLIT1(u1.w, hi[7], lo[7])                \
}

// 3-MFMA scaled split product (separate accM, for LO_SCALE'd operands)
#define MM(accH, accM, a_h, a_l, b_h, b_l) {                                   \
    accH = __builtin_amdgcn_mfma_f32_16x16x32_f16(a_h, b_h, accH, 0, 0, 0);    \
    accM = __builtin_amdgcn_mfma_f32_16x16x32_f16(a_l, b_h, accM, 0, 0, 0);    \
    accM = __builtin_amdgcn_mfma_f32_16x16x32_f16(a_h, b_l, accM, 0, 0, 0);    \
}
// 3-MFMA unscaled split product (O(1) data: lo is fp16-normal, one acc)
#define MM1(acc, a_h, a_l, b_h, b_l) {                                         \
    acc = __builtin_amdgcn_mfma_f32_16x16x32_f16(a_h, b_h, acc, 0, 0, 0);      \
    acc = __builtin_amdgcn_mfma_f32_16x16x32_f16(a_l, b_h, acc, 0, 0, 0);      \
    acc = __builtin_amdgcn_mfma_f32_16x16x32_f16(a_h, b_l, acc, 0, 0, 0);      \
}

// ---- prep body: W fp32 -> fp16 hi + scaled-lo bricks (262144 halves each)
__device__ __forceinline__ void prep_one(
    const float* __restrict__ W, _Float16* __restrict__ whi,
    _Float16* __restrict__ wlo, int g)
{
    const int kk = g >> 7;
    const int n  = (g & 127) * 4;
    const float4 f = *(const float4*)(W + (size_t)kk * DM + n);
    const int gbase = (kk >> 3) * 128 + (kk & 7);
    #define PREP1(val, nn) {                                             \
        const int a_ = ((nn) >> 4) * 8192 + gbase + ((nn) & 15) * 8;     \
        _Float16 h_; _Float16 l_;                                        \
        SPLIT1(val, h_, l_)                                              \
        whi[a_] = h_; wlo[a_] = l_;                                      \
    }
    PREP1(f.x, n + 0) PREP1(f.y, n + 1) PREP1(f.z, n + 2) PREP1(f.w, n + 3)
    #undef PREP1
}

__global__ __launch_bounds__(256) void k_prep_qkv(
    const float* __restrict__ wq, const float* __restrict__ wk,
    const float* __restrict__ wv, float* __restrict__ attn)
{
    const int w = blockIdx.y;
    const float* W = (w == 0) ? wq : (w == 1) ? wk : wv;
    _Float16* base = (_Float16*)attn + (size_t)w * 524288;
    prep_one(W, base, base + 262144, blockIdx.x * 256 + threadIdx.x);
}

__global__ __launch_bounds__(256) void k_prep_wo(
    const float* __restrict__ wo, float* __restrict__ ws)
{
    _Float16* base = (_Float16*)(ws + OFF_VH);
    prep_one(wo, base, base + 262144, blockIdx.x * 256 + threadIdx.x);
}

// ---- aux fold: aux[b][i][j] = f16( mask*(-1e9*at) + hb*t_hb + pi*t_pi ), clamped.
// Written into d_out's out region (8MB, dead until k_out).
__global__ __launch_bounds__(256) void k_prep_aux(
    const float* __restrict__ mask, const float* __restrict__ t_hb,
    const float* __restrict__ t_pi,
    const float* __restrict__ aug_hb, const float* __restrict__ aug_pi,
    const float* __restrict__ aug_at, const int* __restrict__ bnum,
    float* __restrict__ outp)
{
    const int g = blockIdx.x * 256 + threadIdx.x;       // 0..1M-1
    const size_t e0 = (size_t)g * 4;
    const size_t t0 = e0 & (size_t)(NS*NS - 1);
    const int bn = bnum[0];
    const float at = aug_at[bn], hb = aug_hb[bn], pi = aug_pi[bn];
    const float m_at = -1e9f * at;
    const f4 m4 = *(const f4*)(mask + e0);
    const f4 th = *(const f4*)(t_hb + t0);
    const f4 tp = *(const f4*)(t_pi + t0);
    h4 o;
    float a;
    a = fmaf(m4.x, m_at, fmaf(hb, th.x, pi*tp.x)); if (a < -60000.f) a = -60000.f; o[0] = (_Float16)a;
    a = fmaf(m4.y, m_at, fmaf(hb, th.y, pi*tp.y)); if (a < -60000.f) a = -60000.f; o[1] = (_Float16)a;
    a = fmaf(m4.z, m_at, fmaf(hb, th.z, pi*tp.z)); if (a < -60000.f) a = -60000.f; o[2] = (_Float16)a;
    a = fmaf(m4.w, m_at, fmaf(hb, th.w, pi*tp.w)); if (a < -60000.f) a = -60000.f; o[3] = (_Float16)a;
    *(h4*)((_Float16*)outp + e0) = o;
}

// ---------------- QKV projection via fp16-split MFMA: X@W+b -> split heads
// q/k results written as f16 hi/lo planes [bh][s][d] (lo at +65536 halves);
// v written fp32 (k_pv consumes it).
__global__ __launch_bounds__(256, 3) void k_proj(
    const float* __restrict__ q, const float* __restrict__ k, const float* __restrict__ v,
    const float* __restrict__ bq, const float* __restrict__ bk, const float* __restrict__ bv,
    float* __restrict__ ws, const float* __restrict__ attn)
{
    const float *X, *bias; int wsel;
    if (blockIdx.z == 0)      { X=q; bias=bq; wsel=0; }
    else if (blockIdx.z == 1) { X=k; bias=bk; wsel=1; }
    else                      { X=v; bias=bv; wsel=2; }
    float* outf = ws + OFF_VH;                       // v only
    _Float16* outh = (_Float16*)(ws + (wsel == 0 ? OFF_QH : OFF_KH));  // q/k

    const int f = blockIdx.x + (blockIdx.y << 3);       // 0..255
    const int n0 = (f >> 5) * 64, m0 = (f & 31) * 128;
    const int tid = threadIdx.x, l = tid & 63, w = tid >> 6;
    const int lr = l & 15, lg = l >> 4;

    const _Float16* whi = (const _Float16*)attn + (size_t)wsel * 524288;
    const _Float16* wlo = whi + 262144;
    const float* ap0 = X + (size_t)(m0 + w*32 + lr) * DM + lg*8;
    const float* ap1 = ap0 + (size_t)16 * DM;
    const _Float16* bh_base = whi + (size_t)(n0 >> 4) * 8192 + lg*128 + lr*8;
    const _Float16* bl_base = wlo + (size_t)(n0 >> 4) * 8192 + lg*128 + lr*8;

    f32x4v aH00 = 0, aH01 = 0, aH02 = 0, aH03 = 0;
    f32x4v aH10 = 0, aH11 = 0, aH12 = 0, aH13 = 0;
    f32x4v aM00 = 0, aM01 = 0, aM02 = 0, aM03 = 0;
    f32x4v aM10 = 0, aM11 = 0, aM12 = 0, aM13 = 0;

    #pragma unroll 1
    for (int kb = 0; kb < DM; kb += 32) {
        h8 ah0, al0, ah1, al1;
        {
            const float4 u0 = *(const float4*)(ap0 + kb);
            const float4 u1 = *(const float4*)(ap0 + kb + 4);
            SPLIT8(u0, u1, ah0, al0);
            const float4 v0 = *(const float4*)(ap1 + kb);
            const float4 v1 = *(const float4*)(ap1 + kb + 4);
            SPLIT8(v0, v1, ah1, al1);
        }
        const int boff = kb * 16;
        const h8 bh0 = *(const h8*)(bh_base + boff);
        const h8 bh1 = *(const h8*)(bh_base + boff + 8192);
        const h8 bh2 = *(const h8*)(bh_base + boff + 16384);
        const h8 bh3 = *(const h8*)(bh_base + boff + 24576);
        const h8 bl0 = *(const h8*)(bl_base + boff);
        const h8 bl1 = *(const h8*)(bl_base + boff + 8192);
        const h8 bl2 = *(const h8*)(bl_base + boff + 16384);
        const h8 bl3 = *(const h8*)(bl_base + boff + 24576);

        MM(aH00, aM00, ah0, al0, bh0, bl0) MM(aH01, aM01, ah0, al0, bh1, bl1)
        MM(aH02, aM02, ah0, al0, bh2, bl2) MM(aH03, aM03, ah0, al0, bh3, bl3)
        MM(aH10, aM10, ah1, al1, bh0, bl0) MM(aH11, aM11, ah1, al1, bh1, bl1)
        MM(aH12, aM12, ah1, al1, bh2, bl2) MM(aH13, aM13, ah1, al1, bh3, bl3)
    }

    const int h = n0 >> 6;
    #define STORE_TILE(accH, accM, nt, mt) {                                 \
        const int n = n0 + (nt)*16 + lr;                                     \
        const float bsv = bias[n];                                           \
        const int d = n & 63;                                                \
        const int mbase = m0 + w*32 + (mt)*16 + lg*4;                        \
        _Pragma("unroll")                                                    \
        for (int r = 0; r < 4; ++r) {                                        \
            const int m = mbase + r;                                         \
            const int bb = m >> 10, s = m & 1023;                            \
            const float val = fmaf(accM[r], LO_INV, accH[r]) + bsv;          \
            if (wsel == 2) {                                                 \
                outf[(((size_t)(bb*NH + h))*NS + s)*DEPTH + d] = val;        \
            } else {                                                         \
                _Float16* p = outh + (size_t)(bb*NH + h)*131072              \
                                   + (size_t)s*64 + d;                       \
                const _Float16 hi_ = (_Float16)val;                          \
                p[0]     = hi_;                                              \
                p[65536] = (_Float16)(val - (float)hi_);                     \
            }                                                                \
        }                                                                    \
    }
    STORE_TILE(aH00, aM00, 0, 0) STORE_TILE(aH10, aM10, 0, 1)
    STORE_TILE(aH01, aM01, 1, 0) STORE_TILE(aH11, aM11, 1, 1)
    STORE_TILE(aH02, aM02, 2, 0) STORE_TILE(aH12, aM12, 2, 1)
    STORE_TILE(aH03, aM03, 3, 0) STORE_TILE(aH13, aM13, 3, 1)
    #undef STORE_TILE
}

// ---------------- k_score: S = K.Q^T via MFMA (R12 orientation: A=K rows i, B=Q rows j)
// e = exp(acc*sc_at + aux) -> plain (cached) scalar store + partial sums.
// 128x128 tile, 4 waves x (32i x 128j), no LDS, no K-loop barriers.
// launch_bounds (256,4): 64 VGPR + 64 AGPR = 128 = 512/4 exactly (R17 ran (256,3) @ 38% occ).
__global__ __launch_bounds__(256, 4) void k_score(
    float* __restrict__ ws,
    const _Float16* __restrict__ aux,
    const float* __restrict__ aug_at, const int* __restrict__ bnum,
    float* __restrict__ attn)
{
    __shared__ float wred[4];
    const int bh = blockIdx.z, b = bh >> 3;
    const int f = blockIdx.x + (blockIdx.y << 3);  // 0..63, rect XCD grouping
    const int r = f & 7, qq = f >> 3;
    const int it = ((r & 1) << 2) | (qq & 3);
    const int jt_ = ((r >> 1) << 1) | (qq >> 2);
    const int i0 = it * 128, j0 = jt_ * 128;
    const _Float16* kb_ = (const _Float16*)(ws + OFF_KH) + (size_t)bh * 131072;
    const _Float16* qb_ = (const _Float16*)(ws + OFF_QH) + (size_t)bh * 131072;
    const int tid = threadIdx.x, l = tid & 63, w = tid >> 6;
    const int lr = l & 15, lg = l >> 4;

    // wave w covers i-rows [i0 + w*32, +32) x all 128 j
    const _Float16* ka = kb_ + (size_t)(i0 + w*32 + lr) * 64 + lg*8;
    const _Float16* qa = qb_ + (size_t)(j0 + lr) * 64 + lg*8;

    f32x4v acc[2][8] = {};
    #pragma unroll
    for (int d0 = 0; d0 < 2; ++d0) {
        const int dd = d0 * 32;
        const h8 ah0 = *(const h8*)(ka + dd);
        const h8 al0 = *(const h8*)(ka + dd + 65536);
        const h8 ah1 = *(const h8*)(ka + dd + 16*64);
        const h8 al1 = *(const h8*)(ka + dd + 16*64 + 65536);
        #pragma unroll
        for (int jt = 0; jt < 8; ++jt) {
            const h8 bhf = *(const h8*)(qa + dd + jt*16*64);
            const h8 blf = *(const h8*)(qa + dd + jt*16*64 + 65536);
            MM1(acc[0][jt], ah0, al0, bhf, blf)
            MM1(acc[1][jt], ah1, al1, bhf, blf)
        }
    }

    // D[m=i][n=j]: lane holds i = i0+w*32+it2*16+lg*4+reg, j = j0+jt*16+lr (fixed)
    const int bn = bnum[0];
    const float sc_at = 0.125f * aug_at[bn];
    float local = 0.f;
    #pragma unroll
    for (int it2 = 0; it2 < 2; ++it2) {
        #pragma unroll
        for (int rr = 0; rr < 4; ++rr) {
            const int gi = i0 + w*32 + it2*16 + lg*4 + rr;
            const size_t xrow = ((size_t)b*NS + gi)*NS;
            const size_t arow = ((size_t)bh*NS + gi)*NS;
            #pragma unroll
            for (int jt = 0; jt < 8; ++jt) {
                const int gj = j0 + jt*16 + lr;
                const float xv = (float)aux[xrow + gj];
                const float e = __expf(fmaf(acc[it2][jt][rr], sc_at, xv));
                attn[arow + gj] = e;            // plain cached store (stays in L2/L3 for k_pv)
                local += e;
            }
        }
    }
    #pragma unroll
    for (int o = 32; o > 0; o >>= 1) local += __shfl_down(local, o);
    if ((tid & 63) == 0) wred[tid >> 6] = local;
    __syncthreads();
    if (tid == 0)
        ws[OFF_PART + bh*64 + it*8 + jt_] =
            (wred[0] + wred[1]) + (wred[2] + wred[3]);
}

// ---------------- k_pv: inv-reduce + read e (cached), write attn=e*inv, ctx_partial=(e*inv)@V
__global__ __launch_bounds__(256, 4) void k_pv(
    float* __restrict__ ws, float* __restrict__ attn)
{
    __shared__ float Es[64][68];    // [j][i], ESW-swizzled
    __shared__ float Vs[64][68];    // [j][d]
    __shared__ float s_inv;
    const int F = blockIdx.x + (blockIdx.y << 1) + (blockIdx.z << 5);  // 0..1023
    const int r = F & 7, s = F >> 3;
    const int bh = (r << 2) | (s & 3);
    const int w = s >> 2;
    const int i0 = (w >> 1) * 64;
    const int jh = w & 1;
    const int b = bh >> 3, h = bh & 7;
    const float* vh = ws + OFF_VH + (size_t)bh*NS*DEPTH;
    float* pctx = ws + (jh ? OFF_CTX1 : OFF_CTX0);
    const int tid = threadIdx.x, tx = tid & 15, ty = tid >> 4;
    const int er_ = tid >> 4, ec4 = tid & 15;

    if (tid < 64) {
        float vsum = ws[OFF_PART + bh*64 + tid];
        #pragma unroll
        for (int o = 32; o > 0; o >>= 1) vsum += __shfl_down(vsum, o);
        if (tid == 0) s_inv = 1.0f / vsum;
    }
    __syncthreads();
    const float inv = s_inv;

    float acc[4][4] = {};
    for (int jt = 0; jt < 8; ++jt) {
        const int j0 = jh*512 + jt*64;
        #pragma unroll
        for (int l = 0; l < 4; ++l) {
            const int rr = er_ + l*16;
            float* ap = attn + ((size_t)bh*NS + i0 + rr)*NS + j0 + ec4*4;
            f4 e4 = *(const f4*)ap;
            e4 *= inv;
            *(f4*)ap = e4;                     // final normalized attn
            Es[ec4*4+0][ESW(ec4*4+0, rr)] = e4.x;
            Es[ec4*4+1][ESW(ec4*4+1, rr)] = e4.y;
            Es[ec4*4+2][ESW(ec4*4+2, rr)] = e4.z;
            Es[ec4*4+3][ESW(ec4*4+3, rr)] = e4.w;
            *(float4*)&Vs[rr][ec4*4] = *(const float4*)(vh + (size_t)(j0+rr)*DEPTH + ec4*4);
        }
        __syncthreads();
        #pragma unroll
        for (int jj = 0; jj < 64; ++jj) {
            const float4 a  = *(const float4*)&Es[jj][ESW(jj, ty*4)];
            const float4 vv = *(const float4*)&Vs[jj][tx*4];
            const float av[4] = {a.x,a.y,a.z,a.w};
            const float vw[4] = {vv.x,vv.y,vv.z,vv.w};
            #pragma unroll
            for (int i = 0; i < 4; ++i)
                #pragma unroll
                for (int d = 0; d < 4; ++d)
                    acc[i][d] = fmaf(av[i], vw[d], acc[i][d]);
        }
        __syncthreads();
    }
    #pragma unroll
    for (int i = 0; i < 4; ++i) {
        const int gi = i0 + ty*4 + i;
        float4 o;
        o.x = acc[i][0]; o.y = acc[i][1]; o.z = acc[i][2]; o.w = acc[i][3];
        *(float4*)(pctx + ((size_t)b*NS + gi)*DM + h*DEPTH + tx*4) = o;
    }
}

// ---------------- out = (ctx0+ctx1) @ wo + b via fp16-split MFMA (ctx pre-scaled)
__global__ __launch_bounds__(256, 3) void k_out(
    const float* __restrict__ wsc, const float* __restrict__ bo,
    float* __restrict__ outp)
{
    const int f = blockIdx.x + (blockIdx.y << 3);       // grid MUST be (8,32)
    const int n0 = (f >> 5) * 64, m0 = (f & 31) * 128;
    const int tid = threadIdx.x, l = tid & 63, w = tid >> 6;
    const int lr = l & 15, lg = l >> 4;

    const _Float16* whi = (const _Float16*)(wsc + OFF_VH);
    const _Float16* wlo = whi + 262144;
    const float* ap0 = wsc + OFF_CTX0 + (size_t)(m0 + w*32 + lr) * DM + lg*8;
    const float* ap1 = wsc + OFF_CTX1 + (size_t)(m0 + w*32 + lr) * DM + lg*8;
    const _Float16* bh_base = whi + (size_t)(n0 >> 4) * 8192 + lg*128 + lr*8;
    const _Float16* bl_base = wlo + (size_t)(n0 >> 4) * 8192 + lg*128 + lr*8;

    f32x4v aH00 = 0, aH01 = 0, aH02 = 0, aH03 = 0;
    f32x4v aH10 = 0, aH11 = 0, aH12 = 0, aH13 = 0;
    f32x4v aM00 = 0, aM01 = 0, aM02 = 0, aM03 = 0;
    f32x4v aM10 = 0, aM11 = 0, aM12 = 0, aM13 = 0;

    #pragma unroll 1
    for (int kb = 0; kb < DM; kb += 32) {
        h8 ah0, al0, ah1, al1;
        {
            float4 u0 = *(const float4*)(ap0 + kb);
            float4 u1 = *(const float4*)(ap0 + kb + 4);
            const float4 c0 = *(const float4*)(ap1 + kb);
            const float4 c1 = *(const float4*)(ap1 + kb + 4);
            u0.x=(u0.x+c0.x)*ASCALE; u0.y=(u0.y+c0.y)*ASCALE;
            u0.z=(u0.z+c0.z)*ASCALE; u0.w=(u0.w+c0.w)*ASCALE;
            u1.x=(u1.x+c1.x)*ASCALE; u1.y=(u1.y+c1.y)*ASCALE;
            u1.z=(u1.z+c1.z)*ASCALE; u1.w=(u1.w+c1.w)*ASCALE;
            SPLIT8(u0, u1, ah0, al0);
            float4 v0 = *(const float4*)(ap0 + (size_t)16*DM + kb);
            float4 v1 = *(const float4*)(ap0 + (size_t)16*DM + kb + 4);
            const float4 d0 = *(const float4*)(ap1 + (size_t)16*DM + kb);
            const float4 d1 = *(const float4*)(ap1 + (size_t)16*DM + kb + 4);
            v0.x=(v0.x+d0.x)*ASCALE; v0.y=(v0.y+d0.y)*ASCALE;
            v0.z=(v0.z+d0.z)*ASCALE; v0.w=(v0.w+d0.w)*ASCALE;
            v1.x=(v1.x+d1.x)*ASCALE; v1.y=(v1.y+d1.y)*ASCALE;
            v1.z=(v1.z+d1.z)*ASCALE; v1.w=(v1.w+d1.w)*ASCALE;
            SPLIT8(v0, v1, ah1, al1);
        }
        const int boff = kb * 16;
        const h8 bh0 = *(const h8*)(bh_base + boff);
        const h8 bh1 = *(const h8*)(bh_base + boff + 8192);
        const h8 bh2 = *(const h8*)(bh_base + boff + 16384);
        const h8 bh3 = *(const h8*)(bh_base + boff + 24576);
        const h8 bl0 = *(const h8*)(bl_base + boff);
        const h8 bl1 = *(const h8*)(bl_base + boff + 8192);
        const h8 bl2 = *(const h8*)(bl_base + boff + 16384);
        const h8 bl3 = *(const h8*)(bl_base + boff + 24576);

        MM(aH00, aM00, ah0, al0, bh0, bl0) MM(aH01, aM01, ah0, al0, bh1, bl1)
        MM(aH02, aM02, ah0, al0, bh2, bl2) MM(aH03, aM03, ah0, al0, bh3, bl3)
        MM(aH10, aM10, ah1, al1, bh0, bl0) MM(aH11, aM11, ah1, al1, bh1, bl1)
        MM(aH12, aM12, ah1, al1, bh2, bl2) MM(aH13, aM13, ah1, al1, bh3, bl3)
    }

    #define STORE_TILE(accH, accM, nt, mt) {                                 \
        const int n = n0 + (nt)*16 + lr;                                     \
        const float bsv = bo[n];                                             \
        const int mbase = m0 + w*32 + (mt)*16 + lg*4;                        \
        _Pragma("unroll")                                                    \
        for (int r = 0; r < 4; ++r)                                          \
            outp[(size_t)(mbase + r)*DM + n] =                               \
                fmaf(accM[r], LO_INV, accH[r]) * AUNSCALE + bsv;             \
    }
    STORE_TILE(aH00, aM00, 0, 0) STORE_TILE(aH10, aM10, 0, 1)
    STORE_TILE(aH01, aM01, 1, 0) STORE_TILE(aH11, aM11, 1, 1)
    STORE_TILE(aH02, aM02, 2, 0) STORE_TILE(aH12, aM12, 2, 1)
    STORE_TILE(aH03, aM03, 3, 0) STORE_TILE(aH13, aM13, 3, 1)
    #undef STORE_TILE
}

extern "C" void kernel_launch(void* const* d_in, const int* in_sizes, int n_in,
                              void* d_out, int out_size, void* d_ws, size_t ws_size,
                              hipStream_t stream)
{
    const float* v    = (const float*)d_in[0];
    const float* q    = (const float*)d_in[1];
    const float* k    = (const float*)d_in[2];
    const float* wq_w = (const float*)d_in[3];
    const float* wq_b = (const float*)d_in[4];
    const float* wk_w = (const float*)d_in[5];
    const float* wk_b = (const float*)d_in[6];
    const float* wv_w = (const float*)d_in[7];
    const float* wv_b = (const float*)d_in[8];
    const float* wo_w = (const float*)d_in[9];
    const float* wo_b = (const float*)d_in[10];
    const float* aug_hb = (const float*)d_in[11];
    const float* aug_pi = (const float*)d_in[12];
    const float* aug_at = (const float*)d_in[13];
    const float* t_hb   = (const float*)d_in[14];
    const float* t_pi   = (const float*)d_in[15];
    const float* mask   = (const float*)d_in[16];
    const int*   bnum   = (const int*)d_in[17];

    float* ws   = (float*)d_ws;
    float* outp = (float*)d_out;
    float* attn = (float*)d_out + (size_t)4*NS*DM;

    // 1. wq/wk/wv bricks into d_out attn region (overwritten later by k_score)
    hipLaunchKernelGGL(k_prep_qkv, dim3(256, 3), dim3(256), 0, stream,
                       wq_w, wk_w, wv_w, attn);
    // 1b. aux f16 plane (mask+tables folded) into d_out out region (dead until k_out)
    hipLaunchKernelGGL(k_prep_aux, dim3(4096), dim3(256), 0, stream,
                       mask, t_hb, t_pi, aug_hb, aug_pi, aug_at, bnum, outp);
    // 2. projections (MFMA); q/k -> f16 hi/lo planes, v -> fp32
    hipLaunchKernelGGL(k_proj, dim3(8, 32, 3), dim3(256), 0, stream,
                       q, k, v, wq_b, wk_b, wv_b, ws, attn);
    // 3. scores via MFMA + e + partial sums (reads aux; R12 orientation, cached stores)
    hipLaunchKernelGGL(k_score, dim3(8, 8, 32), dim3(256), 0, stream,
                       ws, (const _Float16*)outp, aug_at, bnum, attn);
    // 4. PV + attn normalization (VH dead afterwards)
    hipLaunchKernelGGL(k_pv, dim3(2, 16, 32), dim3(256), 0, stream, ws, attn);
    // 5. wo bricks into the now-dead VH region
    hipLaunchKernelGGL(k_prep_wo, dim3(256, 1), dim3(256), 0, stream, wo_w, ws);
    // 6. output projection (MFMA), grid (8,32) = 256 blocks exactly; overwrites aux
    hipLaunchKernelGGL(k_out, dim3(8, 32), dim3(256), 0, stream,
                       ws, wo_b, outp);
}